// Round 8
// baseline (424.095 us; speedup 1.0000x reference)
//
#include <hip/hip_runtime.h>
#include <hip/hip_bf16.h>
#include <stdint.h>

// MMoE: E=16 experts, T=4 tasks, H=512, I=1024, B=8192.
// out[t,b] = sum_e g[b,t,e] * (sum_h relu(x@We^T+be)[b,e,h] * Wf[t,h]) + bf[t]
// R7 finding: ~80 µs is fixed harness overhead (restore/poison/launch);
// small kernels are ~28 µs; only lever left is the 196.8 µs main GEMM
// (MfmaUtil 31%, MFMA+VALU=56% vs m97's 80% -> barrier-drain stalls).
// R8: BK 32->64 (half the vmcnt(0)+barrier drains), staging 32 KB with
// allsums union'd into dead staging; swizzle re-derived for 8-chunk rows
// (slot = chunk ^ (row&7)). Epilogue + all other kernels unchanged.

#define E_ 16
#define T_ 4
#define H_ 512
#define I_ 1024
#define B_ 8192
#define N_ (E_ * H_) /* 8192 */
#define K_ I_        /* 1024 */

typedef __bf16 bf16x8 __attribute__((ext_vector_type(8)));
typedef float f32x4 __attribute__((ext_vector_type(4)));

__device__ __forceinline__ unsigned short f2bf_rne(float f) {
  unsigned int b = __float_as_uint(f);
  b += 0x7fffu + ((b >> 16) & 1u);
  return (unsigned short)(b >> 16);
}

#define N4X (B_ * K_ / 4) /* 2097152 */
#define N4W (N_ * K_ / 4) /* 2097152 */
#define N4G (64 * K_ / 4) /* 16384 */

// merged fp32 -> bf16 (RNE) for x | We | Wg, float4 in / ushort4 out
__global__ __launch_bounds__(256) void cvt3_kernel(const float* __restrict__ x,
                                                   const float* __restrict__ We,
                                                   const float* __restrict__ Wg,
                                                   unsigned short* __restrict__ xb,
                                                   unsigned short* __restrict__ wb,
                                                   unsigned short* __restrict__ wgb) {
  int i = blockIdx.x * 256 + threadIdx.x;
  const float* src;
  unsigned short* dst;
  int j;
  if (i < N4X) {
    src = x; dst = xb; j = i;
  } else if (i < N4X + N4W) {
    src = We; dst = wb; j = i - N4X;
  } else if (i < N4X + N4W + N4G) {
    src = Wg; dst = wgb; j = i - (N4X + N4W);
  } else {
    return;
  }
  float4 v = reinterpret_cast<const float4*>(src)[j];
  ushort4 o;
  o.x = f2bf_rne(v.x);
  o.y = f2bf_rne(v.y);
  o.z = f2bf_rne(v.z);
  o.w = f2bf_rne(v.w);
  reinterpret_cast<ushort4*>(dst)[j] = o;
}

__device__ __forceinline__ void gld_lds16(const void* gp, void* lp) {
  __builtin_amdgcn_global_load_lds((const __attribute__((address_space(1))) void*)gp,
                                   (__attribute__((address_space(3))) void*)lp, 16, 0, 0);
}

// logits L[b][te] = x[b,:]@Wg[te,:] + bg[te] via bf16 MFMA (Wg [T][E][I] is
// already B^T [64][1024]), then softmax over e (= the 16 m16-lanes) in
// registers -> g[b][64]. Tile: M=128, N=64, BK=32; 4 waves x 32 rows each.
__global__ __launch_bounds__(256) void logits_softmax_kernel(
    const unsigned short* __restrict__ A,    // x bf16 [B_][K_]
    const unsigned short* __restrict__ Bm,   // Wg bf16 [64][K_]
    const float* __restrict__ bg,            // [64]
    float* __restrict__ g)                   // [B_][64]
{
  __shared__ struct {
    unsigned short A[128 * 32];  // 8 KB
    unsigned short B[64 * 32];   // 4 KB
  } st;

  const int tid = threadIdx.x;
  const int w = tid >> 6, l = tid & 63;
  const int m16 = l & 15, q = l >> 4;
  const size_t m0 = (size_t)blockIdx.x * 128;

  // A staging: rows w*32..w*32+31, 2 chunks/thread
  const int r0s = (w * 2 + 0) * 16 + (l >> 2);
  const int r1s = (w * 2 + 1) * 16 + (l >> 2);
  const int slot = l & 3;
  const int c0 = slot ^ ((r0s >> 1) & 3);
  const int c1 = slot ^ ((r1s >> 1) & 3);
  const size_t offA0 = (m0 + r0s) * K_ + c0 * 8;
  const size_t offA1 = (m0 + r1s) * K_ + c1 * 8;
  const int l0 = (w * 2 + 0) * 512;
  const int l1 = (w * 2 + 1) * 512;
  // B staging: 64 rows, 1 chunk/thread; wave w covers rows w*16..w*16+15
  const int rBs = w * 16 + (l >> 2);
  const int cB = slot ^ ((rBs >> 1) & 3);
  const size_t offB = (size_t)rBs * K_ + cB * 8;
  const int lB = w * 512;

  const int arow = w * 32 + m16;
  const int sA = q ^ ((arow >> 1) & 3);
  const int sB = q ^ ((m16 >> 1) & 3);

  f32x4 acc[2][4] = {};

  for (int k0 = 0; k0 < K_; k0 += 32) {
    __syncthreads();
    gld_lds16(A + offA0 + k0, st.A + l0);
    gld_lds16(A + offA1 + k0, st.A + l1);
    gld_lds16(Bm + offB + k0, st.B + lB);
    __syncthreads();
    bf16x8 af[2], bfr[4];
#pragma unroll
    for (int i = 0; i < 2; ++i)
      af[i] = *reinterpret_cast<const bf16x8*>(st.A + (arow + i * 16) * 32 + sA * 8);
#pragma unroll
    for (int j = 0; j < 4; ++j)
      bfr[j] = *reinterpret_cast<const bf16x8*>(st.B + (j * 16 + m16) * 32 + sB * 8);
#pragma unroll
    for (int i = 0; i < 2; ++i)
#pragma unroll
      for (int j = 0; j < 4; ++j)
        acc[i][j] = __builtin_amdgcn_mfma_f32_16x16x32_bf16(af[i], bfr[j], acc[i][j], 0, 0, 0);
  }

  // acc[i][j][r] = L[row = w*32+16i+4q+r][te = j*16+m16]; t = j, e = m16.
  float bgv[4];
#pragma unroll
  for (int j = 0; j < 4; ++j) bgv[j] = bg[j * 16 + m16];

#pragma unroll
  for (int i = 0; i < 2; ++i) {
    float lg[4][4];  // [r][j]
#pragma unroll
    for (int j = 0; j < 4; ++j)
#pragma unroll
      for (int r = 0; r < 4; ++r) lg[r][j] = acc[i][j][r] + bgv[j];
#pragma unroll
    for (int r = 0; r < 4; ++r) {
#pragma unroll
      for (int j = 0; j < 4; ++j) {
        float m = lg[r][j];
#pragma unroll
        for (int mask = 1; mask < 16; mask <<= 1) m = fmaxf(m, __shfl_xor(m, mask, 64));
        float ex = __expf(lg[r][j] - m);
        float s = ex;
#pragma unroll
        for (int mask = 1; mask < 16; mask <<= 1) s += __shfl_xor(s, mask, 64);
        size_t b = m0 + w * 32 + i * 16 + q * 4 + r;
        g[b * 64 + j * 16 + m16] = ex / s;
      }
    }
  }
}

// Main: bf16 GEMM C = A x B^T (fp32 acc), relu+bias, Wf-contraction + gating
// in registers (shfl butterfly over the 16 m16-lanes), per-tile partial to
// global partials[nb][t][b] (deterministic; no atomics).
// 128x128 tile, BK=64 (half the barrier drains of BK=32), 4 waves x 4x4 of
// 16x16x32 MFMA x 2 k-halves, global_load_lds width=16, slot=chunk^(row&7).
__global__ __launch_bounds__(256, 2) void moe_main_kernel(
    const unsigned short* __restrict__ A,   // x bf16 [B_][K_]
    const unsigned short* __restrict__ Bm,  // We bf16 [N_][K_]
    const float* __restrict__ be,           // [E_*H_] flat == indexed by n
    const float* __restrict__ Wf,           // [T_][H_]
    const float* __restrict__ g,            // [B_][64] (t*16+e)
    float* __restrict__ partials)           // [64 nb][T_][B_]
{
  __shared__ union {
    struct {
      unsigned short A[128 * 64];
      unsigned short B[128 * 64];
    } st;                     // 32 KB staging
    float allsums[2 * 512];   // reused after K-loop (staging dead)
  } sm;

  const int tid = threadIdx.x;
  const int w = tid >> 6, l = tid & 63;
  const int wm = w >> 1, wn = w & 1;
  const int m16 = l & 15, q = l >> 4;
  const int nb = blockIdx.x, mb = blockIdx.y;
  const size_t m0 = (size_t)mb * 128, n0 = (size_t)nb * 128;

  // staging: rows of 64 bf16 = 8 chunks of 16B; chunk c of row r at slot c^(r&7).
  // Wave w stages rows w*32..w*32+31 (4 gld x 8 rows) for A and B.
  // One gld fills 8 rows: lane l -> row +(l>>3), LDS slot l&7, global chunk (l&7)^(l>>3).
  const int srow = l >> 3;
  const int cg = (l & 7) ^ srow;
  size_t goffA[4], goffB[4];
#pragma unroll
  for (int k = 0; k < 4; ++k) {
    int row = w * 32 + k * 8 + srow;
    goffA[k] = (m0 + row) * K_ + cg * 8;
    goffB[k] = (n0 + row) * K_ + cg * 8;
  }

  const int arow = wm * 64 + m16;
  const int brow = wn * 64 + m16;
  // fragment slot for k-half h: (4h+q) ^ (row&7); arow&7 == brow&7 == m16&7
  const int sf0 = q ^ (m16 & 7);
  const int sf1 = (4 + q) ^ (m16 & 7);

  f32x4 acc[4][4] = {};

  for (int k0 = 0; k0 < K_; k0 += 64) {
    __syncthreads();
#pragma unroll
    for (int k = 0; k < 4; ++k) {
      gld_lds16(A + goffA[k] + k0, sm.st.A + (w * 32 + k * 8) * 64);
      gld_lds16(Bm + goffB[k] + k0, sm.st.B + (w * 32 + k * 8) * 64);
    }
    __syncthreads();  // vmcnt(0) drain before barrier
#pragma unroll
    for (int h = 0; h < 2; ++h) {
      const int sf = h ? sf1 : sf0;
      bf16x8 af[4], bfr[4];
#pragma unroll
      for (int i = 0; i < 4; ++i)
        af[i] = *reinterpret_cast<const bf16x8*>(sm.st.A + (arow + i * 16) * 64 + sf * 8);
#pragma unroll
      for (int j = 0; j < 4; ++j)
        bfr[j] = *reinterpret_cast<const bf16x8*>(sm.st.B + (brow + j * 16) * 64 + sf * 8);
#pragma unroll
      for (int i = 0; i < 4; ++i)
#pragma unroll
        for (int j = 0; j < 4; ++j)
          acc[i][j] = __builtin_amdgcn_mfma_f32_16x16x32_bf16(af[i], bfr[j], acc[i][j], 0, 0, 0);
    }
  }

  __syncthreads();  // staging LDS dead; union'd allsums becomes live

  const int hbase = (int)(n0 & 511);  // h-offset of this tile (expert = n0>>9)

  // Per-lane epilogue: lane's acc element (i,j,reg) is
  // D[row = wm*64+16i+4q+reg][col = wn*64+16j+m16]  (C/D: col=lane&15, row=4*(lane>>4)+reg)
  float wfv[4][4];  // [t][j]
#pragma unroll
  for (int t = 0; t < 4; ++t)
#pragma unroll
    for (int j = 0; j < 4; ++j)
      wfv[t][j] = Wf[t * H_ + hbase + wn * 64 + j * 16 + m16];
  float bias[4];
#pragma unroll
  for (int j = 0; j < 4; ++j) bias[j] = be[n0 + wn * 64 + j * 16 + m16];

  const int reg_sel = m16 >> 2, t_sel = m16 & 3;  // slot this lane owns after reduce
#pragma unroll
  for (int i = 0; i < 4; ++i) {
    float eo[4][4];  // [j][reg]
#pragma unroll
    for (int j = 0; j < 4; ++j)
#pragma unroll
      for (int r = 0; r < 4; ++r) eo[j][r] = fmaxf(acc[i][j][r] + bias[j], 0.f);
    float p[16];  // [reg*4 + t] partial over this lane's 4 cols
#pragma unroll
    for (int r = 0; r < 4; ++r)
#pragma unroll
      for (int t = 0; t < 4; ++t) {
        float v = 0.f;
#pragma unroll
        for (int j = 0; j < 4; ++j) v += eo[j][r] * wfv[t][j];
        p[r * 4 + t] = v;
      }
    // butterfly-sum over the 16 m16-lanes (same q => same rows, disjoint cols)
#pragma unroll
    for (int mask = 1; mask < 16; mask <<= 1)
#pragma unroll
      for (int s = 0; s < 16; ++s) p[s] += __shfl_xor(p[s], mask, 64);
    // lane keeps slot s = m16
    float v = p[0];
#pragma unroll
    for (int s = 1; s < 16; ++s) v = (m16 == s) ? p[s] : v;
    int row = wm * 64 + i * 16 + q * 4 + reg_sel;
    sm.allsums[wn * 512 + row * 4 + t_sel] = v;
  }
  __syncthreads();

  // combine wn-halves, apply gate, emit per-tile partial (deterministic)
  const int e_idx = (int)(n0 >> 9);
#pragma unroll
  for (int oi = 0; oi < 2; ++oi) {
    int o = tid * 2 + oi;  // 512 = 128 rows x 4 t
    int row = o >> 2, t = o & 3;
    float s = sm.allsums[row * 4 + t] + sm.allsums[512 + row * 4 + t];
    size_t b = m0 + row;
    float gv = g[b * 64 + t * 16 + e_idx];
    partials[(size_t)nb * (T_ * B_) + (size_t)t * B_ + b] = gv * s;
  }
}

// out[t,b] = bf[t] + sum_nb partials[nb][t][b]
__global__ __launch_bounds__(128) void reduce_kernel(const float* __restrict__ partials,
                                                     const float* __restrict__ bfv,
                                                     float* __restrict__ out) {
  int i = blockIdx.x * 128 + threadIdx.x;  // T_*B_ = 32768
  float s = bfv[i >> 13];
#pragma unroll 4
  for (int nb = 0; nb < 64; ++nb) s += partials[(size_t)nb * (T_ * B_) + i];
  out[i] = s;
}

extern "C" void kernel_launch(void* const* d_in, const int* in_sizes, int n_in,
                              void* d_out, int out_size, void* d_ws, size_t ws_size,
                              hipStream_t stream) {
  const float* x = (const float*)d_in[0];   // [B, I]
  const float* We = (const float*)d_in[1];  // [E, H, I]
  const float* be = (const float*)d_in[2];  // [E, H]
  const float* Wg = (const float*)d_in[3];  // [T, E, I]
  const float* bg = (const float*)d_in[4];  // [T, E]
  const float* Wf = (const float*)d_in[5];  // [T, H]
  const float* bf = (const float*)d_in[6];  // [T]
  float* out = (float*)d_out;               // [T, B, 1]

  // ws: xb (16.8MB) | wb (16.8MB) | wgb (0.13MB) | g (2.1MB) | partials (8.4MB)
  unsigned short* xb = (unsigned short*)d_ws;
  unsigned short* wb = xb + (size_t)B_ * K_;
  unsigned short* wgb = wb + (size_t)N_ * K_;
  float* g = (float*)(wgb + (size_t)64 * K_);
  float* partials = g + (size_t)B_ * 64;

  cvt3_kernel<<<(N4X + N4W + N4G + 255) / 256, 256, 0, stream>>>(x, We, Wg, xb, wb, wgb);
  logits_softmax_kernel<<<B_ / 128, 256, 0, stream>>>(xb, wgb, bg, g);
  dim3 grid(N_ / 128, B_ / 128);
  moe_main_kernel<<<grid, 256, 0, stream>>>(xb, wb, be, Wf, g, partials);
  reduce_kernel<<<(T_ * B_) / 128, 128, 0, stream>>>(partials, bf, out);
}

// Round 9
// 291.268 us; speedup vs baseline: 1.4560x; 1.4560x over previous
//
#include <hip/hip_runtime.h>
#include <hip/hip_bf16.h>
#include <stdint.h>

// MMoE: E=16 experts, T=4 tasks, H=512, I=1024, B=8192.
// out[t,b] = sum_e g[b,t,e] * (sum_h relu(x@We^T+be)[b,e,h] * Wf[t,h]) + bf[t]
// R8 finding: BK=64 with 128B-row-stride swizzle caused 1.008e8 LDS bank
// conflicts (~160 µs) -> regression. The drain-halving hypothesis was never
// tested. R9: BK=64 as TWO 128x32 buffers, each with the R7 HW-verified
// 64B-stride layout (0 conflicts measured) -> 16 barrier-pairs instead of 32,
// layout risk removed. Epilogue + logits + cvt3 + reduce identical to R7.

#define E_ 16
#define T_ 4
#define H_ 512
#define I_ 1024
#define B_ 8192
#define N_ (E_ * H_) /* 8192 */
#define K_ I_        /* 1024 */

typedef __bf16 bf16x8 __attribute__((ext_vector_type(8)));
typedef float f32x4 __attribute__((ext_vector_type(4)));

__device__ __forceinline__ unsigned short f2bf_rne(float f) {
  unsigned int b = __float_as_uint(f);
  b += 0x7fffu + ((b >> 16) & 1u);
  return (unsigned short)(b >> 16);
}

#define N4X (B_ * K_ / 4) /* 2097152 */
#define N4W (N_ * K_ / 4) /* 2097152 */
#define N4G (64 * K_ / 4) /* 16384 */

// merged fp32 -> bf16 (RNE) for x | We | Wg, float4 in / ushort4 out
__global__ __launch_bounds__(256) void cvt3_kernel(const float* __restrict__ x,
                                                   const float* __restrict__ We,
                                                   const float* __restrict__ Wg,
                                                   unsigned short* __restrict__ xb,
                                                   unsigned short* __restrict__ wb,
                                                   unsigned short* __restrict__ wgb) {
  int i = blockIdx.x * 256 + threadIdx.x;
  const float* src;
  unsigned short* dst;
  int j;
  if (i < N4X) {
    src = x; dst = xb; j = i;
  } else if (i < N4X + N4W) {
    src = We; dst = wb; j = i - N4X;
  } else if (i < N4X + N4W + N4G) {
    src = Wg; dst = wgb; j = i - (N4X + N4W);
  } else {
    return;
  }
  float4 v = reinterpret_cast<const float4*>(src)[j];
  ushort4 o;
  o.x = f2bf_rne(v.x);
  o.y = f2bf_rne(v.y);
  o.z = f2bf_rne(v.z);
  o.w = f2bf_rne(v.w);
  reinterpret_cast<ushort4*>(dst)[j] = o;
}

__device__ __forceinline__ void gld_lds16(const void* gp, void* lp) {
  __builtin_amdgcn_global_load_lds((const __attribute__((address_space(1))) void*)gp,
                                   (__attribute__((address_space(3))) void*)lp, 16, 0, 0);
}

// logits L[b][te] = x[b,:]@Wg[te,:] + bg[te] via bf16 MFMA (Wg [T][E][I] is
// already B^T [64][1024]), then softmax over e (= the 16 m16-lanes) in
// registers -> g[b][64]. Tile: M=128, N=64, BK=32; 4 waves x 32 rows each.
__global__ __launch_bounds__(256) void logits_softmax_kernel(
    const unsigned short* __restrict__ A,    // x bf16 [B_][K_]
    const unsigned short* __restrict__ Bm,   // Wg bf16 [64][K_]
    const float* __restrict__ bg,            // [64]
    float* __restrict__ g)                   // [B_][64]
{
  __shared__ struct {
    unsigned short A[128 * 32];  // 8 KB
    unsigned short B[64 * 32];   // 4 KB
  } st;

  const int tid = threadIdx.x;
  const int w = tid >> 6, l = tid & 63;
  const int m16 = l & 15, q = l >> 4;
  const size_t m0 = (size_t)blockIdx.x * 128;

  // A staging: rows w*32..w*32+31, 2 chunks/thread
  const int r0s = (w * 2 + 0) * 16 + (l >> 2);
  const int r1s = (w * 2 + 1) * 16 + (l >> 2);
  const int slot = l & 3;
  const int c0 = slot ^ ((r0s >> 1) & 3);
  const int c1 = slot ^ ((r1s >> 1) & 3);
  const size_t offA0 = (m0 + r0s) * K_ + c0 * 8;
  const size_t offA1 = (m0 + r1s) * K_ + c1 * 8;
  const int l0 = (w * 2 + 0) * 512;
  const int l1 = (w * 2 + 1) * 512;
  // B staging: 64 rows, 1 chunk/thread; wave w covers rows w*16..w*16+15
  const int rBs = w * 16 + (l >> 2);
  const int cB = slot ^ ((rBs >> 1) & 3);
  const size_t offB = (size_t)rBs * K_ + cB * 8;
  const int lB = w * 512;

  const int arow = w * 32 + m16;
  const int sA = q ^ ((arow >> 1) & 3);
  const int sB = q ^ ((m16 >> 1) & 3);

  f32x4 acc[2][4] = {};

  for (int k0 = 0; k0 < K_; k0 += 32) {
    __syncthreads();
    gld_lds16(A + offA0 + k0, st.A + l0);
    gld_lds16(A + offA1 + k0, st.A + l1);
    gld_lds16(Bm + offB + k0, st.B + lB);
    __syncthreads();
    bf16x8 af[2], bfr[4];
#pragma unroll
    for (int i = 0; i < 2; ++i)
      af[i] = *reinterpret_cast<const bf16x8*>(st.A + (arow + i * 16) * 32 + sA * 8);
#pragma unroll
    for (int j = 0; j < 4; ++j)
      bfr[j] = *reinterpret_cast<const bf16x8*>(st.B + (j * 16 + m16) * 32 + sB * 8);
#pragma unroll
    for (int i = 0; i < 2; ++i)
#pragma unroll
      for (int j = 0; j < 4; ++j)
        acc[i][j] = __builtin_amdgcn_mfma_f32_16x16x32_bf16(af[i], bfr[j], acc[i][j], 0, 0, 0);
  }

  // acc[i][j][r] = L[row = w*32+16i+4q+r][te = j*16+m16]; t = j, e = m16.
  float bgv[4];
#pragma unroll
  for (int j = 0; j < 4; ++j) bgv[j] = bg[j * 16 + m16];

#pragma unroll
  for (int i = 0; i < 2; ++i) {
    float lg[4][4];  // [r][j]
#pragma unroll
    for (int j = 0; j < 4; ++j)
#pragma unroll
      for (int r = 0; r < 4; ++r) lg[r][j] = acc[i][j][r] + bgv[j];
#pragma unroll
    for (int r = 0; r < 4; ++r) {
#pragma unroll
      for (int j = 0; j < 4; ++j) {
        float m = lg[r][j];
#pragma unroll
        for (int mask = 1; mask < 16; mask <<= 1) m = fmaxf(m, __shfl_xor(m, mask, 64));
        float ex = __expf(lg[r][j] - m);
        float s = ex;
#pragma unroll
        for (int mask = 1; mask < 16; mask <<= 1) s += __shfl_xor(s, mask, 64);
        size_t b = m0 + w * 32 + i * 16 + q * 4 + r;
        g[b * 64 + j * 16 + m16] = ex / s;
      }
    }
  }
}

// Main: bf16 GEMM C = A x B^T (fp32 acc), relu+bias, Wf-contraction + gating
// in registers (shfl butterfly over the 16 m16-lanes), per-tile partial to
// global partials[nb][t][b] (deterministic; no atomics).
// 128x128 tile, BK=64 as TWO 128x32 buffers with the R7-verified 64B-stride
// staging/swizzle each (0 conflicts) -> 16 barrier-pairs instead of 32.
__global__ __launch_bounds__(256, 2) void moe_main_kernel(
    const unsigned short* __restrict__ A,   // x bf16 [B_][K_]
    const unsigned short* __restrict__ Bm,  // We bf16 [N_][K_]
    const float* __restrict__ be,           // [E_*H_] flat == indexed by n
    const float* __restrict__ Wf,           // [T_][H_]
    const float* __restrict__ g,            // [B_][64] (t*16+e)
    float* __restrict__ partials)           // [64 nb][T_][B_]
{
  __shared__ union {
    struct {
      unsigned short A0[128 * 32];
      unsigned short A1[128 * 32];
      unsigned short B0[128 * 32];
      unsigned short B1[128 * 32];
    } st;                    // 32 KB staging (two verified 64B-stride buffers)
    float allsums[2 * 512];  // reused after K-loop (staging dead)
  } sm;

  const int tid = threadIdx.x;
  const int w = tid >> 6, l = tid & 63;
  const int wm = w >> 1, wn = w & 1;
  const int m16 = l & 15, q = l >> 4;
  const int nb = blockIdx.x, mb = blockIdx.y;
  const size_t m0 = (size_t)mb * 128, n0 = (size_t)nb * 128;

  // staging (per 32-wide buffer): LDS row-major [128][4 chunks of 16B];
  // chunk c of row r at slot c^((r>>1)&3). 2 rows/thread per buffer.
  const int r0s = (w * 2 + 0) * 16 + (l >> 2);
  const int r1s = (w * 2 + 1) * 16 + (l >> 2);
  const int slot = l & 3;
  const int c0 = slot ^ ((r0s >> 1) & 3);
  const int c1 = slot ^ ((r1s >> 1) & 3);
  const size_t offA0 = (m0 + r0s) * K_ + c0 * 8;
  const size_t offA1 = (m0 + r1s) * K_ + c1 * 8;
  const size_t offB0 = (n0 + r0s) * K_ + c0 * 8;
  const size_t offB1 = (n0 + r1s) * K_ + c1 * 8;
  const int l0 = (w * 2 + 0) * 512;  // wave-uniform LDS base (HW adds lane*16)
  const int l1 = (w * 2 + 1) * 512;

  const int arow = wm * 64 + m16;
  const int brow = wn * 64 + m16;
  const int sA = q ^ ((arow >> 1) & 3);  // constant over i: (i*16)>>1 ≡ 0 mod 4
  const int sB = q ^ ((brow >> 1) & 3);

  f32x4 acc[4][4] = {};

  for (int k0 = 0; k0 < K_; k0 += 64) {
    __syncthreads();
    // k-half 0 -> buffers A0/B0; k-half 1 (k0+32) -> buffers A1/B1
    gld_lds16(A + offA0 + k0, sm.st.A0 + l0);
    gld_lds16(A + offA1 + k0, sm.st.A0 + l1);
    gld_lds16(A + offA0 + k0 + 32, sm.st.A1 + l0);
    gld_lds16(A + offA1 + k0 + 32, sm.st.A1 + l1);
    gld_lds16(Bm + offB0 + k0, sm.st.B0 + l0);
    gld_lds16(Bm + offB1 + k0, sm.st.B0 + l1);
    gld_lds16(Bm + offB0 + k0 + 32, sm.st.B1 + l0);
    gld_lds16(Bm + offB1 + k0 + 32, sm.st.B1 + l1);
    __syncthreads();  // vmcnt(0) drain before barrier (once per 64-wide K-tile)
#pragma unroll
    for (int h = 0; h < 2; ++h) {
      const unsigned short* bufA = h ? sm.st.A1 : sm.st.A0;
      const unsigned short* bufB = h ? sm.st.B1 : sm.st.B0;
      bf16x8 af[4], bfr[4];
#pragma unroll
      for (int i = 0; i < 4; ++i)
        af[i] = *reinterpret_cast<const bf16x8*>(bufA + (arow + i * 16) * 32 + sA * 8);
#pragma unroll
      for (int j = 0; j < 4; ++j)
        bfr[j] = *reinterpret_cast<const bf16x8*>(bufB + (brow + j * 16) * 32 + sB * 8);
#pragma unroll
      for (int i = 0; i < 4; ++i)
#pragma unroll
        for (int j = 0; j < 4; ++j)
          acc[i][j] = __builtin_amdgcn_mfma_f32_16x16x32_bf16(af[i], bfr[j], acc[i][j], 0, 0, 0);
    }
  }

  __syncthreads();  // staging LDS dead; union'd allsums becomes live

  const int hbase = (int)(n0 & 511);  // h-offset of this tile (expert = n0>>9)

  // Per-lane epilogue: lane's acc element (i,j,reg) is
  // D[row = wm*64+16i+4q+reg][col = wn*64+16j+m16]  (C/D: col=lane&15, row=4*(lane>>4)+reg)
  float wfv[4][4];  // [t][j]
#pragma unroll
  for (int t = 0; t < 4; ++t)
#pragma unroll
    for (int j = 0; j < 4; ++j)
      wfv[t][j] = Wf[t * H_ + hbase + wn * 64 + j * 16 + m16];
  float bias[4];
#pragma unroll
  for (int j = 0; j < 4; ++j) bias[j] = be[n0 + wn * 64 + j * 16 + m16];

  const int reg_sel = m16 >> 2, t_sel = m16 & 3;  // slot this lane owns after reduce
#pragma unroll
  for (int i = 0; i < 4; ++i) {
    float eo[4][4];  // [j][reg]
#pragma unroll
    for (int j = 0; j < 4; ++j)
#pragma unroll
      for (int r = 0; r < 4; ++r) eo[j][r] = fmaxf(acc[i][j][r] + bias[j], 0.f);
    float p[16];  // [reg*4 + t] partial over this lane's 4 cols
#pragma unroll
    for (int r = 0; r < 4; ++r)
#pragma unroll
      for (int t = 0; t < 4; ++t) {
        float v = 0.f;
#pragma unroll
        for (int j = 0; j < 4; ++j) v += eo[j][r] * wfv[t][j];
        p[r * 4 + t] = v;
      }
    // butterfly-sum over the 16 m16-lanes (same q => same rows, disjoint cols)
#pragma unroll
    for (int mask = 1; mask < 16; mask <<= 1)
#pragma unroll
      for (int s = 0; s < 16; ++s) p[s] += __shfl_xor(p[s], mask, 64);
    // lane keeps slot s = m16
    float v = p[0];
#pragma unroll
    for (int s = 1; s < 16; ++s) v = (m16 == s) ? p[s] : v;
    int row = wm * 64 + i * 16 + q * 4 + reg_sel;
    sm.allsums[wn * 512 + row * 4 + t_sel] = v;
  }
  __syncthreads();

  // combine wn-halves, apply gate, emit per-tile partial (deterministic)
  const int e_idx = (int)(n0 >> 9);
#pragma unroll
  for (int oi = 0; oi < 2; ++oi) {
    int o = tid * 2 + oi;  // 512 = 128 rows x 4 t
    int row = o >> 2, t = o & 3;
    float s = sm.allsums[row * 4 + t] + sm.allsums[512 + row * 4 + t];
    size_t b = m0 + row;
    float gv = g[b * 64 + t * 16 + e_idx];
    partials[(size_t)nb * (T_ * B_) + (size_t)t * B_ + b] = gv * s;
  }
}

// out[t,b] = bf[t] + sum_nb partials[nb][t][b]
__global__ __launch_bounds__(128) void reduce_kernel(const float* __restrict__ partials,
                                                     const float* __restrict__ bfv,
                                                     float* __restrict__ out) {
  int i = blockIdx.x * 128 + threadIdx.x;  // T_*B_ = 32768
  float s = bfv[i >> 13];
#pragma unroll 4
  for (int nb = 0; nb < 64; ++nb) s += partials[(size_t)nb * (T_ * B_) + i];
  out[i] = s;
}

extern "C" void kernel_launch(void* const* d_in, const int* in_sizes, int n_in,
                              void* d_out, int out_size, void* d_ws, size_t ws_size,
                              hipStream_t stream) {
  const float* x = (const float*)d_in[0];   // [B, I]
  const float* We = (const float*)d_in[1];  // [E, H, I]
  const float* be = (const float*)d_in[2];  // [E, H]
  const float* Wg = (const float*)d_in[3];  // [T, E, I]
  const float* bg = (const float*)d_in[4];  // [T, E]
  const float* Wf = (const float*)d_in[5];  // [T, H]
  const float* bf = (const float*)d_in[6];  // [T]
  float* out = (float*)d_out;               // [T, B, 1]

  // ws: xb (16.8MB) | wb (16.8MB) | wgb (0.13MB) | g (2.1MB) | partials (8.4MB)
  unsigned short* xb = (unsigned short*)d_ws;
  unsigned short* wb = xb + (size_t)B_ * K_;
  unsigned short* wgb = wb + (size_t)N_ * K_;
  float* g = (float*)(wgb + (size_t)64 * K_);
  float* partials = g + (size_t)B_ * 64;

  cvt3_kernel<<<(N4X + N4W + N4G + 255) / 256, 256, 0, stream>>>(x, We, Wg, xb, wb, wgb);
  logits_softmax_kernel<<<B_ / 128, 256, 0, stream>>>(xb, wgb, bg, g);
  dim3 grid(N_ / 128, B_ / 128);
  moe_main_kernel<<<grid, 256, 0, stream>>>(xb, wb, be, Wf, g, partials);
  reduce_kernel<<<(T_ * B_) / 128, 128, 0, stream>>>(partials, bf, out);
}